// Round 1
// baseline (8776.417 us; speedup 1.0000x reference)
//
#include <hip/hip_runtime.h>
#include <hip/hip_fp16.h>

#define BB 32
#define LL 512
#define HH 1024
#define NL 4

typedef _Float16 f16x8 __attribute__((ext_vector_type(8)));
typedef float    f32x4 __attribute__((ext_vector_type(4)));

// ---- convert f32 weights -> f16 (once per call, into workspace) ----
__global__ __launch_bounds__(256) void cvt_weights(const float* __restrict__ src,
                                                   _Float16* __restrict__ dst, int n) {
  int i = (blockIdx.x * 256 + threadIdx.x) * 8;
  if (i >= n) return;
  f32x4 a = *reinterpret_cast<const f32x4*>(src + i);
  f32x4 b = *reinterpret_cast<const f32x4*>(src + i + 4);
  f16x8 h;
#pragma unroll
  for (int e = 0; e < 4; ++e) { h[e] = (_Float16)a[e]; h[e + 4] = (_Float16)b[e]; }
  *reinterpret_cast<f16x8*>(dst + i) = h;
}

// ---- one wavefront stage: 4 concurrent (layer, t=stage-layer) GEMM+tanh tasks ----
// grid: 256 blocks x 64 threads (1 wave). blocks [l*64 .. l*64+63] handle layer l,
// each block computes 16 output columns x 32 batch rows (2 MFMA 16x16 tiles).
__global__ __launch_bounds__(64) void rnn_stage(
    const float* __restrict__ x,        // [B][L][H] f32
    const float* __restrict__ h0,       // [NL][B][H] f32
    const _Float16* __restrict__ WIh,   // [NL][H][H] f16
    const _Float16* __restrict__ WHh,   // [NL][H][H] f16
    const float* __restrict__ BI,       // [NL][H]
    const float* __restrict__ BH,       // [NL][H]
    float* __restrict__ out,            // [B][L][H] f32, then hfinal [NL][B][H]
    _Float16* __restrict__ hbuf,        // [NL][2][B][H] f16 ring
    int stage) {
  const int l = blockIdx.x >> 6;
  const int t = stage - l;
  if (t < 0 || t >= LL) return;
  const int blk  = blockIdx.x & 63;
  const int c0   = blk * 16;
  const int lane = threadIdx.x;
  const int crow = lane & 15;   // A-row / B-col / D-col index
  const int kgrp = lane >> 4;   // k-group 0..3

  f32x4 acc0 = {0.f, 0.f, 0.f, 0.f};
  f32x4 acc1 = {0.f, 0.f, 0.f, 0.f};

  // ================= input half: inp @ WI[l]^T =================
  {
    const _Float16* wr = WIh + ((size_t)l * HH + (c0 + crow)) * HH;
    if (l == 0) {
      // inp = x[:, t, :], f32 -> convert to f16 fragments on the fly
      const float* xr0 = x + ((size_t)crow * LL + t) * HH;
      const float* xr1 = x + ((size_t)(crow + 16) * LL + t) * HH;
#pragma unroll 4
      for (int ks = 0; ks < HH; ks += 32) {
        const int k = ks + kgrp * 8;
        f32x4 a0lo = *reinterpret_cast<const f32x4*>(xr0 + k);
        f32x4 a0hi = *reinterpret_cast<const f32x4*>(xr0 + k + 4);
        f32x4 a1lo = *reinterpret_cast<const f32x4*>(xr1 + k);
        f32x4 a1hi = *reinterpret_cast<const f32x4*>(xr1 + k + 4);
        f16x8 a0, a1;
#pragma unroll
        for (int e = 0; e < 4; ++e) {
          a0[e] = (_Float16)a0lo[e]; a0[e + 4] = (_Float16)a0hi[e];
          a1[e] = (_Float16)a1lo[e]; a1[e + 4] = (_Float16)a1hi[e];
        }
        f16x8 b = *reinterpret_cast<const f16x8*>(wr + k);
        acc0 = __builtin_amdgcn_mfma_f32_16x16x32_f16(a0, b, acc0, 0, 0, 0);
        acc1 = __builtin_amdgcn_mfma_f32_16x16x32_f16(a1, b, acc1, 0, 0, 0);
      }
    } else {
      // inp = hbuf[l-1][t&1], f16
      const _Float16* ir0 = hbuf + ((((size_t)(l - 1) * 2 + (t & 1)) * BB) + crow) * HH;
      const _Float16* ir1 = ir0 + (size_t)16 * HH;
#pragma unroll 4
      for (int ks = 0; ks < HH; ks += 32) {
        const int k = ks + kgrp * 8;
        f16x8 a0 = *reinterpret_cast<const f16x8*>(ir0 + k);
        f16x8 a1 = *reinterpret_cast<const f16x8*>(ir1 + k);
        f16x8 b  = *reinterpret_cast<const f16x8*>(wr + k);
        acc0 = __builtin_amdgcn_mfma_f32_16x16x32_f16(a0, b, acc0, 0, 0, 0);
        acc1 = __builtin_amdgcn_mfma_f32_16x16x32_f16(a1, b, acc1, 0, 0, 0);
      }
    }
  }

  // ================= hidden half: h_prev @ WH[l]^T =================
  {
    const _Float16* wr = WHh + ((size_t)l * HH + (c0 + crow)) * HH;
    if (t == 0) {
      // h_prev = h0[l], f32 -> convert
      const float* hr0 = h0 + ((size_t)l * BB + crow) * HH;
      const float* hr1 = hr0 + (size_t)16 * HH;
#pragma unroll 4
      for (int ks = 0; ks < HH; ks += 32) {
        const int k = ks + kgrp * 8;
        f32x4 a0lo = *reinterpret_cast<const f32x4*>(hr0 + k);
        f32x4 a0hi = *reinterpret_cast<const f32x4*>(hr0 + k + 4);
        f32x4 a1lo = *reinterpret_cast<const f32x4*>(hr1 + k);
        f32x4 a1hi = *reinterpret_cast<const f32x4*>(hr1 + k + 4);
        f16x8 a0, a1;
#pragma unroll
        for (int e = 0; e < 4; ++e) {
          a0[e] = (_Float16)a0lo[e]; a0[e + 4] = (_Float16)a0hi[e];
          a1[e] = (_Float16)a1lo[e]; a1[e + 4] = (_Float16)a1hi[e];
        }
        f16x8 b = *reinterpret_cast<const f16x8*>(wr + k);
        acc0 = __builtin_amdgcn_mfma_f32_16x16x32_f16(a0, b, acc0, 0, 0, 0);
        acc1 = __builtin_amdgcn_mfma_f32_16x16x32_f16(a1, b, acc1, 0, 0, 0);
      }
    } else {
      const _Float16* hr0 = hbuf + ((((size_t)l * 2 + ((t - 1) & 1)) * BB) + crow) * HH;
      const _Float16* hr1 = hr0 + (size_t)16 * HH;
#pragma unroll 4
      for (int ks = 0; ks < HH; ks += 32) {
        const int k = ks + kgrp * 8;
        f16x8 a0 = *reinterpret_cast<const f16x8*>(hr0 + k);
        f16x8 a1 = *reinterpret_cast<const f16x8*>(hr1 + k);
        f16x8 b  = *reinterpret_cast<const f16x8*>(wr + k);
        acc0 = __builtin_amdgcn_mfma_f32_16x16x32_f16(a0, b, acc0, 0, 0, 0);
        acc1 = __builtin_amdgcn_mfma_f32_16x16x32_f16(a1, b, acc1, 0, 0, 0);
      }
    }
  }

  // ================= bias + tanh + stores =================
  const int c = c0 + crow;
  const float bias = BI[l * HH + c] + BH[l * HH + c];
  _Float16* hout = hbuf + (((size_t)l * 2 + (t & 1)) * BB) * HH;

#pragma unroll
  for (int r = 0; r < 4; ++r) {
    const int b0 = kgrp * 4 + r;        // D row (batch) for tile 0; tile 1 is b0+16
    const float v0 = tanhf(acc0[r] + bias);
    const float v1 = tanhf(acc1[r] + bias);
    hout[(size_t)b0 * HH + c]        = (_Float16)v0;
    hout[(size_t)(b0 + 16) * HH + c] = (_Float16)v1;
    if (l == NL - 1) {   // last layer -> output[b][t][c]
      out[((size_t)b0 * LL + t) * HH + c]        = v0;
      out[((size_t)(b0 + 16) * LL + t) * HH + c] = v1;
    }
    if (t == LL - 1) {   // h_final[l][b][c]
      float* hf = out + (size_t)BB * LL * HH + (size_t)l * BB * HH;
      hf[(size_t)b0 * HH + c]        = v0;
      hf[(size_t)(b0 + 16) * HH + c] = v1;
    }
  }
}

extern "C" void kernel_launch(void* const* d_in, const int* in_sizes, int n_in,
                              void* d_out, int out_size, void* d_ws, size_t ws_size,
                              hipStream_t stream) {
  const float* x  = (const float*)d_in[0];
  const float* h0 = (const float*)d_in[1];
  const float* WI = (const float*)d_in[2];
  const float* BI = (const float*)d_in[3];
  const float* WH = (const float*)d_in[4];
  const float* BH = (const float*)d_in[5];
  float* out = (float*)d_out;

  const int nW = NL * HH * HH;                  // 4M elems per weight tensor
  _Float16* WIh  = (_Float16*)d_ws;             // 8 MB
  _Float16* WHh  = WIh + (size_t)nW;            // 8 MB
  _Float16* hbuf = WHh + (size_t)nW;            // [NL][2][B][H] f16, 512 KB

  cvt_weights<<<nW / 8 / 256, 256, 0, stream>>>(WI, WIh, nW);
  cvt_weights<<<nW / 8 / 256, 256, 0, stream>>>(WH, WHh, nW);

  for (int s = 0; s < LL + NL - 1; ++s) {
    rnn_stage<<<256, 64, 0, stream>>>(x, h0, WIh, WHh, BI, BH, out, hbuf, s);
  }
}